// Round 4
// baseline (1117.566 us; speedup 1.0000x reference)
//
#include <hip/hip_runtime.h>
#include <hip/hip_bf16.h>

#define NN  50000
#define EE  300000
#define HH  256
#define TDD 768
#define NBB 8
#define TTT 8192

typedef __bf16 bf16x8 __attribute__((ext_vector_type(8)));
typedef float  f32x4  __attribute__((ext_vector_type(4)));
typedef unsigned short u16x8 __attribute__((ext_vector_type(8)));

__device__ __forceinline__ float b2f(unsigned short u) {
    union { unsigned int i; float f; } v; v.i = (unsigned int)u << 16; return v.f;
}
__device__ __forceinline__ unsigned short f2b(float f) {
    union { float f; unsigned int i; } v; v.f = f;
    unsigned int r = (v.i + 0x7fffu + ((v.i >> 16) & 1u)) >> 16;
    return (unsigned short)r;
}
__device__ __forceinline__ void gload16(const void* g, void* l) {
    __builtin_amdgcn_global_load_lds(
        (const __attribute__((address_space(1))) void*)g,
        (__attribute__((address_space(3))) void*)l, 16, 0, 0);
}

// ---------------------------------------------------------------------------
// bf16 MFMA GEMM, tall-skinny:  C[M,256] = A[M,K] @ Bt[256,K]^T  (+ epilogue)
// BM=64, BN=256 (full width -> A read ONCE), BK=32, 4 waves, wave owns 64x64.
// Depth-1 prefetch double-buffer: stage tile t+1 while computing tile t.
// ADT 0: A bf16, staged via global_load_lds (A split at KS: A1/lda1, A2/lda2)
// ADT 1: A f32 (A1 only), reg-staged: issue loads early, cvt+ds_write late.
// EPI 2: C = relu(acc + bias[n])                     (rgcn layer)
// EPI 3: C = LN(acc + add[m,n] + bias[n]) * g + b    (proj + fused LayerNorm)
// LDS panels chunk-major: slot = cg*ROWS + r, 16B/slot; frag read at
// (lk*ROWS + row)*16 -> same conflict-free pattern as round-3 (verified 0).
// ---------------------------------------------------------------------------
template<int EPI, int ADT>
__global__ __launch_bounds__(256) void gemm16_k(
    const void* __restrict__ A1v, int lda1,
    const void* __restrict__ A2v, int lda2, int KS,
    const unsigned short* __restrict__ Bt, int K,
    unsigned short* __restrict__ C, int M,
    const float* __restrict__ add, const float* __restrict__ bias,
    const float* __restrict__ lng, const float* __restrict__ lnb)
{
    __shared__ unsigned short As[2][2048];   // 64 rows x 32 k   (4 KB x2)
    __shared__ unsigned short Bs[2][8192];   // 256 rows x 32 k  (16 KB x2)
    __shared__ float lredS[64][4];
    __shared__ float lredQ[64][4];
    const int tid  = threadIdx.x;
    const int lane = tid & 63;
    const int wid  = tid >> 6;
    const int bm   = blockIdx.x * 64;
    const int lrow = lane & 15;
    const int lk   = lane >> 4;
    const int wn   = wid * 64;
    const int NT   = K / 32;

    f32x4 acc[4][4];
#pragma unroll
    for (int i = 0; i < 4; ++i)
#pragma unroll
        for (int j = 0; j < 4; ++j) acc[i][j] = (f32x4){0.f, 0.f, 0.f, 0.f};

    // ---- staging helpers ----
    auto stageB = [&](int half, int k0) {
#pragma unroll
        for (int p = 0; p < 4; ++p) {
            int q  = p * 4 + wid;                  // 16 blocks of 64 slots
            int cg = q >> 2;
            int r  = (q & 3) * 64 + lane;          // Bt row = C col
            gload16(Bt + (size_t)r * K + k0 + cg * 8, &Bs[half][q * 512]);
        }
    };
    auto stageA0 = [&](int half, int k0) {         // bf16 A via gload_lds
        const unsigned short* Ap; int lda, kb;
        if (k0 < KS) { Ap = (const unsigned short*)A1v; lda = lda1; kb = k0; }
        else         { Ap = (const unsigned short*)A2v; lda = lda2; kb = k0 - KS; }
        int gm = bm + lane; if (gm >= M) gm = M - 1;
        gload16(Ap + (size_t)gm * lda + kb + wid * 8, &As[half][wid * 512]);
    };
    auto loadA1 = [&](int k0, float4& u0, float4& u1) {   // f32 A -> regs
        const float* Ap = (const float*)A1v;
        int cg = tid >> 6, r = tid & 63;
        int gm = bm + r; if (gm >= M) gm = M - 1;
        const float* p = Ap + (size_t)gm * lda1 + k0 + cg * 8;
        u0 = *(const float4*)p;
        u1 = *(const float4*)(p + 4);
    };
    auto writeA1 = [&](int half, float4 u0, float4 u1) {  // cvt + ds_write
        u16x8 o;
        o[0] = f2b(u0.x); o[1] = f2b(u0.y); o[2] = f2b(u0.z); o[3] = f2b(u0.w);
        o[4] = f2b(u1.x); o[5] = f2b(u1.y); o[6] = f2b(u1.z); o[7] = f2b(u1.w);
        *(u16x8*)&As[half][tid * 8] = o;
    };
    auto compute = [&](int half) {
        bf16x8 af[4], bfr[4];
#pragma unroll
        for (int i = 0; i < 4; ++i) {
            af[i]  = *(const bf16x8*)&As[half][(lk * 64  + i * 16 + lrow) * 8];
            bfr[i] = *(const bf16x8*)&Bs[half][(lk * 256 + wn + i * 16 + lrow) * 8];
        }
#pragma unroll
        for (int i = 0; i < 4; ++i)
#pragma unroll
            for (int j = 0; j < 4; ++j)
                acc[i][j] = __builtin_amdgcn_mfma_f32_16x16x32_bf16(
                    af[i], bfr[j], acc[i][j], 0, 0, 0);
    };

    // ---- prologue: stage tile 0 ----
    if (ADT == 0) {
        stageA0(0, 0);
    } else {
        float4 a0, a1;
        loadA1(0, a0, a1);
        writeA1(0, a0, a1);
    }
    stageB(0, 0);

    // ---- main loop: sync (drain tile t) -> issue t+1 -> compute t ----
    int cur = 0;
    for (int t = 0; t < NT; ++t) {
        __syncthreads();                     // vmcnt(0)+lgkmcnt(0)+barrier
        const bool pf = (t + 1 < NT);
        float4 pa0, pa1;
        if (pf) {
            if (ADT == 0) stageA0(cur ^ 1, (t + 1) * 32);
            else          loadA1((t + 1) * 32, pa0, pa1);
            stageB(cur ^ 1, (t + 1) * 32);
        }
        compute(cur);                        // overlaps t+1's HBM latency
        if (pf && ADT == 1) writeA1(cur ^ 1, pa0, pa1);   // loads landed by now
        cur ^= 1;
    }

    // ---- epilogue ----
    if (EPI == 2) {
#pragma unroll
        for (int i = 0; i < 4; ++i) {
#pragma unroll
            for (int j = 0; j < 4; ++j) {
                int col = wn + j * 16 + lrow;
                float bb = bias[col];
                f32x4 v = acc[i][j];
#pragma unroll
                for (int e = 0; e < 4; ++e) {
                    int gm = bm + i * 16 + lk * 4 + e;
                    if (gm < M)
                        C[(size_t)gm * HH + col] = f2b(fmaxf(v[e] + bb, 0.f));
                }
            }
        }
    } else {   // EPI == 3 : fused LayerNorm
        float sum_[4][4] = {};
        float sq_[4][4]  = {};
        // v = acc + ent_emb + text_proj_b (in place), row partial sums
#pragma unroll
        for (int i = 0; i < 4; ++i)
#pragma unroll
            for (int j = 0; j < 4; ++j) {
                int col = wn + j * 16 + lrow;
                float tb = bias[col];
#pragma unroll
                for (int e = 0; e < 4; ++e) {
                    int gm = bm + i * 16 + lk * 4 + e;
                    if (gm >= M) gm = M - 1;
                    float o = acc[i][j][e] + add[(size_t)gm * HH + col] + tb;
                    acc[i][j][e] = o;
                    sum_[i][e] += o;
                    sq_[i][e]  += o * o;
                }
            }
        // reduce across the 16 lanes of each lk-group (cols of this wave)
#pragma unroll
        for (int m = 1; m < 16; m <<= 1)
#pragma unroll
            for (int i = 0; i < 4; ++i)
#pragma unroll
                for (int e = 0; e < 4; ++e) {
                    sum_[i][e] += __shfl_xor(sum_[i][e], m);
                    sq_[i][e]  += __shfl_xor(sq_[i][e],  m);
                }
        if (lrow == 0) {
#pragma unroll
            for (int i = 0; i < 4; ++i)
#pragma unroll
                for (int e = 0; e < 4; ++e) {
                    int rl = i * 16 + lk * 4 + e;
                    lredS[rl][wid] = sum_[i][e];
                    lredQ[rl][wid] = sq_[i][e];
                }
        }
        __syncthreads();
        float mus[4][4], rstds[4][4];
#pragma unroll
        for (int i = 0; i < 4; ++i)
#pragma unroll
            for (int e = 0; e < 4; ++e) {
                int rl = i * 16 + lk * 4 + e;
                float4 s4 = *(const float4*)lredS[rl];
                float4 q4 = *(const float4*)lredQ[rl];
                float mu = (s4.x + s4.y + s4.z + s4.w) * (1.0f / HH);
                float mq = (q4.x + q4.y + q4.z + q4.w) * (1.0f / HH);
                float var = mq - mu * mu;
                mus[i][e]   = mu;
                rstds[i][e] = rsqrtf(var + 1e-5f);
            }
#pragma unroll
        for (int i = 0; i < 4; ++i)
#pragma unroll
            for (int j = 0; j < 4; ++j) {
                int col = wn + j * 16 + lrow;
                float gg = lng[col], bb = lnb[col];
#pragma unroll
                for (int e = 0; e < 4; ++e) {
                    int gm = bm + i * 16 + lk * 4 + e;
                    if (gm < M) {
                        float o = gg * (acc[i][j][e] - mus[i][e]) * rstds[i][e] + bb;
                        C[(size_t)gm * HH + col] = f2b(o);
                    }
                }
            }
    }
}

// ---------------------------------------------------------------------------
// cast f32 -> bf16 (for W)
// ---------------------------------------------------------------------------
__global__ void cast4_k(const float* __restrict__ in, unsigned short* __restrict__ out,
                        int n4)
{
    int i = blockIdx.x * blockDim.x + threadIdx.x;
    if (i >= n4) return;
    float4 v = *(const float4*)(in + (size_t)i * 4);
    ushort4 o;
    o.x = f2b(v.x); o.y = f2b(v.y); o.z = f2b(v.z); o.w = f2b(v.w);
    *(ushort4*)(out + (size_t)i * 4) = o;
}

// transpose-cast basis/root into Bt[256][2304] per layer
__global__ __launch_bounds__(256) void tcast_k(
    const float* __restrict__ basis1, const float* __restrict__ root1,
    const float* __restrict__ basis2, const float* __restrict__ root2,
    unsigned short* __restrict__ Bt1, unsigned short* __restrict__ Bt2)
{
    __shared__ float Ls[64][68];
    int z = blockIdx.z;
    int layer = z / 9, m = z % 9;
    const float* src = layer ? (m < 8 ? basis2 + m * 65536 : root2)
                             : (m < 8 ? basis1 + m * 65536 : root1);
    unsigned short* dst = layer ? Bt2 : Bt1;
    int coloff = (m < 8) ? m * 256 : 2048;
    int ft = blockIdx.x * 64, dt = blockIdx.y * 64;
    int tid = threadIdx.x;
    int rr = tid >> 4, c4 = (tid & 15) << 2;
#pragma unroll
    for (int p = 0; p < 4; ++p) {
        int dl = p * 16 + rr;
        float4 v = *(const float4*)(src + (size_t)(dt + dl) * HH + ft + c4);
        Ls[c4 + 0][dl] = v.x; Ls[c4 + 1][dl] = v.y;
        Ls[c4 + 2][dl] = v.z; Ls[c4 + 3][dl] = v.w;
    }
    __syncthreads();
#pragma unroll
    for (int q = 0; q < 4; ++q) {
        int fl = q * 16 + rr;
        ushort4 o;
        o.x = f2b(Ls[fl][c4 + 0]); o.y = f2b(Ls[fl][c4 + 1]);
        o.z = f2b(Ls[fl][c4 + 2]); o.w = f2b(Ls[fl][c4 + 3]);
        *(ushort4*)(dst + (size_t)(ft + fl) * 2304 + coloff + dt + c4) = o;
    }
}

// ---------------------------------------------------------------------------
// CSR build
// ---------------------------------------------------------------------------
__global__ void hist_k(const int* __restrict__ dst, int* __restrict__ cnt)
{
    int i = blockIdx.x * blockDim.x + threadIdx.x;
    if (i < EE) atomicAdd(&cnt[dst[i]], 1);
}

__global__ void scan_blk_k(const int* __restrict__ cnt, int* __restrict__ rp,
                           int* __restrict__ bsum)
{
    __shared__ int s[256];
    int tid = threadIdx.x;
    int d = blockIdx.x * 256 + tid;
    int v = (d < NN) ? cnt[d] : 0;
    s[tid] = v;
    __syncthreads();
#pragma unroll
    for (int o = 1; o < 256; o <<= 1) {
        int t = (tid >= o) ? s[tid - o] : 0;
        __syncthreads();
        s[tid] += t;
        __syncthreads();
    }
    if (d < NN) rp[d] = s[tid] - v;
    if (tid == 255) bsum[blockIdx.x] = s[255];
}

__global__ void scan_top_k(int* __restrict__ bsum, int* __restrict__ boff, int nb)
{
    __shared__ int s[256];
    int tid = threadIdx.x;
    int v = (tid < nb) ? bsum[tid] : 0;
    s[tid] = v;
    __syncthreads();
#pragma unroll
    for (int o = 1; o < 256; o <<= 1) {
        int t = (tid >= o) ? s[tid - o] : 0;
        __syncthreads();
        s[tid] += t;
        __syncthreads();
    }
    if (tid < nb) boff[tid] = s[tid] - v;
}

__global__ void scan_add_k(int* __restrict__ rp, const int* __restrict__ boff,
                           int* __restrict__ cur, const int* __restrict__ cnt,
                           float* __restrict__ invdeg)
{
    int d = blockIdx.x * blockDim.x + threadIdx.x;
    if (d < NN) {
        int r = rp[d] + boff[d >> 8];
        rp[d] = r;
        cur[d] = r;
        invdeg[d] = 1.0f / fmaxf((float)cnt[d], 1.0f);
    }
    if (d == 0) rp[NN] = EE;
}

__global__ void scatter_k(const int* __restrict__ src, const int* __restrict__ dst,
                          const int* __restrict__ et, int* __restrict__ cur,
                          int* __restrict__ csr_src, int* __restrict__ csr_et)
{
    int e = blockIdx.x * blockDim.x + threadIdx.x;
    if (e >= EE) return;
    int p = atomicAdd(&cur[dst[e]], 1);
    csr_src[p] = src[e];
    csr_et[p]  = et[e];
}

// ---------------------------------------------------------------------------
// Aggregation (bf16 x -> bf16 y), one wave per dst node
// ---------------------------------------------------------------------------
__global__ __launch_bounds__(256) void agg_k(
    const unsigned short* __restrict__ x, const float* __restrict__ comp,
    const int* __restrict__ rp, const int* __restrict__ csr_src,
    const int* __restrict__ csr_et, const float* __restrict__ invdeg,
    unsigned short* __restrict__ y)
{
    int d = blockIdx.x * 4 + (threadIdx.x >> 6);
    if (d >= NN) return;
    int lane = threadIdx.x & 63;
    int beg = rp[d], end = rp[d + 1];

    float4 acc[NBB];
#pragma unroll
    for (int b = 0; b < NBB; ++b) acc[b] = make_float4(0.f, 0.f, 0.f, 0.f);

    for (int e = beg; e < end; ++e) {
        int s = csr_src[e];
        int t = csr_et[e];
        float4 c0 = *(const float4*)(comp + (size_t)t * NBB);
        float4 c1 = *(const float4*)(comp + (size_t)t * NBB + 4);
        ushort4 u = *(const ushort4*)(x + (size_t)s * HH + lane * 4);
        float xv0 = b2f(u.x), xv1 = b2f(u.y), xv2 = b2f(u.z), xv3 = b2f(u.w);
        float cc[NBB] = {c0.x, c0.y, c0.z, c0.w, c1.x, c1.y, c1.z, c1.w};
#pragma unroll
        for (int b = 0; b < NBB; ++b) {
            acc[b].x = fmaf(cc[b], xv0, acc[b].x);
            acc[b].y = fmaf(cc[b], xv1, acc[b].y);
            acc[b].z = fmaf(cc[b], xv2, acc[b].z);
            acc[b].w = fmaf(cc[b], xv3, acc[b].w);
        }
    }
    float sc = invdeg[d];
    unsigned short* yp = y + (size_t)d * (NBB * HH) + lane * 4;
#pragma unroll
    for (int b = 0; b < NBB; ++b) {
        ushort4 o;
        o.x = f2b(acc[b].x * sc); o.y = f2b(acc[b].y * sc);
        o.z = f2b(acc[b].z * sc); o.w = f2b(acc[b].w * sc);
        *(ushort4*)(yp + (size_t)b * HH) = o;
    }
}

// ---------------------------------------------------------------------------
// score (bf16 x, f32 rel)
// ---------------------------------------------------------------------------
__global__ __launch_bounds__(256) void score_k(
    const unsigned short* __restrict__ x, const float* __restrict__ rel,
    const int* __restrict__ heads, const int* __restrict__ rels,
    const int* __restrict__ tails, float* __restrict__ out)
{
    int i = blockIdx.x * 4 + (threadIdx.x >> 6);
    if (i >= TTT) return;
    int lane = threadIdx.x & 63;
    const unsigned short* h = x + (size_t)heads[i] * HH;
    const unsigned short* t = x + (size_t)tails[i] * HH;
    const float*          r = rel + (size_t)rels[i] * HH;
    int j = lane * 2;
    ushort2 hru = *(const ushort2*)(h + j), hiu = *(const ushort2*)(h + 128 + j);
    ushort2 tru = *(const ushort2*)(t + j), tiu = *(const ushort2*)(t + 128 + j);
    float2 rr = *(const float2*)(r + j), ri = *(const float2*)(r + 128 + j);
    float hr0 = b2f(hru.x), hr1 = b2f(hru.y), hi0 = b2f(hiu.x), hi1 = b2f(hiu.y);
    float tr0 = b2f(tru.x), tr1 = b2f(tru.y), ti0 = b2f(tiu.x), ti1 = b2f(tiu.y);
    float acc = hr0 * rr.x * tr0 + hi0 * rr.x * ti0
              + hr0 * ri.x * ti0 - hi0 * ri.x * tr0
              + hr1 * rr.y * tr1 + hi1 * rr.y * ti1
              + hr1 * ri.y * ti1 - hi1 * ri.y * tr1;
#pragma unroll
    for (int o = 1; o < 64; o <<= 1) acc += __shfl_xor(acc, o);
    if (lane == 0) out[i] = acc;
}

// ---------------------------------------------------------------------------
extern "C" void kernel_launch(void* const* d_in, const int* in_sizes, int n_in,
                              void* d_out, int out_size, void* d_ws, size_t ws_size,
                              hipStream_t stream)
{
    const float* ent_emb     = (const float*)d_in[0];
    const float* text_base   = (const float*)d_in[1];
    const float* text_proj_w = (const float*)d_in[2];
    const float* text_proj_b = (const float*)d_in[3];
    const float* ln_g        = (const float*)d_in[4];
    const float* ln_b        = (const float*)d_in[5];
    const float* comp1       = (const float*)d_in[6];
    const float* basis1      = (const float*)d_in[7];
    const float* root1       = (const float*)d_in[8];
    const float* bias1       = (const float*)d_in[9];
    const float* comp2       = (const float*)d_in[10];
    const float* basis2      = (const float*)d_in[11];
    const float* root2       = (const float*)d_in[12];
    const float* bias2       = (const float*)d_in[13];
    const float* rel_emb     = (const float*)d_in[14];
    const int*   edge_src    = (const int*)d_in[15];
    const int*   edge_dst    = (const int*)d_in[16];
    const int*   edge_type   = (const int*)d_in[17];
    const int*   heads       = (const int*)d_in[18];
    const int*   rels        = (const int*)d_in[19];
    const int*   tails       = (const int*)d_in[20];
    float* out = (float*)d_out;

    char* ws = (char*)d_ws;
    size_t off = 0;
    auto carve = [&](size_t bytes) -> void* {
        void* p = ws + off;
        off = (off + bytes + 255) & ~(size_t)255;
        return p;
    };
    unsigned short* x0b  = (unsigned short*)carve((size_t)NN * HH * 2);
    unsigned short* x1b  = (unsigned short*)carve((size_t)NN * HH * 2);
    unsigned short* y16  = (unsigned short*)carve((size_t)NN * NBB * HH * 2);
    unsigned short* W16  = (unsigned short*)carve((size_t)HH * TDD * 2);
    unsigned short* Bt1  = (unsigned short*)carve((size_t)HH * 2304 * 2);
    unsigned short* Bt2  = (unsigned short*)carve((size_t)HH * 2304 * 2);
    int*   cnt     = (int*)  carve((size_t)NN * 4);
    int*   rp      = (int*)  carve((size_t)(NN + 1) * 4);
    int*   cur     = (int*)  carve((size_t)NN * 4);
    float* invdeg  = (float*)carve((size_t)NN * 4);
    int*   csr_src = (int*)  carve((size_t)EE * 4);
    int*   csr_et  = (int*)  carve((size_t)EE * 4);
    int*   bsum    = (int*)  carve(256 * 4);
    int*   boff    = (int*)  carve(256 * 4);

    const dim3 blk(256);
    const int NBLK = (NN + 255) / 256;
    const int GG = (NN + 63) / 64;              // 782 blocks

    // ---- CSR build ----
    hipMemsetAsync(cnt, 0, (size_t)NN * 4, stream);
    hist_k<<<(EE + 255) / 256, blk, 0, stream>>>(edge_dst, cnt);
    scan_blk_k<<<NBLK, blk, 0, stream>>>(cnt, rp, bsum);
    scan_top_k<<<1, blk, 0, stream>>>(bsum, boff, NBLK);
    scan_add_k<<<NBLK, blk, 0, stream>>>(rp, boff, cur, cnt, invdeg);
    scatter_k<<<(EE + 255) / 256, blk, 0, stream>>>(
        edge_src, edge_dst, edge_type, cur, csr_src, csr_et);

    // ---- weight casts (small) ----
    cast4_k<<<(HH * TDD / 4 + 255) / 256, blk, 0, stream>>>(text_proj_w, W16, HH * TDD / 4);
    tcast_k<<<dim3(4, 4, 18), blk, 0, stream>>>(basis1, root1, basis2, root2, Bt1, Bt2);

    // ---- proj + fused LN:  x0b = LN(text_base @ W^T + ent_emb + b) ----
    gemm16_k<3, 1><<<GG, blk, 0, stream>>>(
        text_base, TDD, text_base, TDD, TDD, W16, TDD,
        x0b, NN, ent_emb, text_proj_b, ln_g, ln_b);

    // ---- two RGCN layers ----
    for (int layer = 0; layer < 2; ++layer) {
        const unsigned short* xin  = layer ? x1b : x0b;
        unsigned short*       xout = layer ? x0b : x1b;
        const unsigned short* Bt   = layer ? Bt2 : Bt1;
        const float*          comp = layer ? comp2 : comp1;
        const float*          bias = layer ? bias2 : bias1;

        agg_k<<<(NN + 3) / 4, blk, 0, stream>>>(
            xin, comp, rp, csr_src, csr_et, invdeg, y16);

        gemm16_k<2, 0><<<GG, blk, 0, stream>>>(
            y16, NBB * HH, xin, HH, NBB * HH, Bt, NBB * HH + HH,
            xout, NN, nullptr, bias, nullptr, nullptr);
    }

    // ---- scoring ----
    score_k<<<(TTT + 3) / 4, blk, 0, stream>>>(x0b, rel_emb, heads, rels, tails, out);
}

// Round 7
// 884.531 us; speedup vs baseline: 1.2635x; 1.2635x over previous
//
#include <hip/hip_runtime.h>
#include <hip/hip_bf16.h>

#define NN  50000
#define EE  300000
#define HH  256
#define TDD 768
#define NBB 8
#define TTT 8192

typedef __bf16 bf16x8 __attribute__((ext_vector_type(8)));
typedef float  f32x4  __attribute__((ext_vector_type(4)));
typedef unsigned short u16x8 __attribute__((ext_vector_type(8)));

__device__ __forceinline__ float b2f(unsigned short u) {
    union { unsigned int i; float f; } v; v.i = (unsigned int)u << 16; return v.f;
}
__device__ __forceinline__ unsigned short f2b(float f) {
    union { float f; unsigned int i; } v; v.f = f;
    unsigned int r = (v.i + 0x7fffu + ((v.i >> 16) & 1u)) >> 16;
    return (unsigned short)r;
}
__device__ __forceinline__ void gload16(const void* g, void* l) {
    __builtin_amdgcn_global_load_lds(
        (const __attribute__((address_space(1))) void*)g,
        (__attribute__((address_space(3))) void*)l, 16, 0, 0);
}

// ---------------------------------------------------------------------------
// bf16 MFMA GEMM, tall-skinny:  C[M,256] = A[M,K] @ Bt[256,K]^T  (+ epilogue)
// BM=64, BN=256 (A read once), BK=32, 4 waves, wave owns 64x64 of C.
// Depth-1 prefetch double-buffer.
// COALESCED staging: lane -> (row = lane>>2, chunk = lane&3); 4 lanes read
// 64B contiguous from one row -> 1 transaction/row (vs 64 scattered lines).
// LDS image is then plain row-major [rows][32k]; frag read at
// ((row)*4 + lk)*16B — balanced across all 32 banks.
// ADT 0: A bf16 via global_load_lds (split at KS: A1/lda1, A2/lda2)
// ADT 1: A f32 (A1 only), reg-staged: 4 lanes x 32B per row, cvt+ds_write.
// EPI 2: C = relu(acc + bias[n])                     (rgcn layer)
// EPI 3: C = LN(acc + add[m,n] + bias[n]) * g + b    (proj + fused LayerNorm)
// ---------------------------------------------------------------------------
template<int EPI, int ADT>
__global__ __launch_bounds__(256) void gemm16_k(
    const void* __restrict__ A1v, int lda1,
    const void* __restrict__ A2v, int lda2, int KS,
    const unsigned short* __restrict__ Bt, int K,
    unsigned short* __restrict__ C, int M,
    const float* __restrict__ add, const float* __restrict__ bias,
    const float* __restrict__ lng, const float* __restrict__ lnb)
{
    __shared__ unsigned short As[2][2048];   // 64 rows x 32 k   (4 KB x2)
    __shared__ unsigned short Bs[2][8192];   // 256 rows x 32 k  (16 KB x2)
    __shared__ float lredS[64][4];
    __shared__ float lredQ[64][4];
    const int tid  = threadIdx.x;
    const int lane = tid & 63;
    const int wid  = tid >> 6;
    const int bm   = blockIdx.x * 64;
    const int lrow = lane & 15;
    const int lk   = lane >> 4;
    const int wn   = wid * 64;
    const int NT   = K / 32;
    const int rsel = lane >> 2;   // row within 16-row group
    const int csel = lane & 3;    // 16B chunk within the row's 64B

    f32x4 acc[4][4];
#pragma unroll
    for (int i = 0; i < 4; ++i)
#pragma unroll
        for (int j = 0; j < 4; ++j) acc[i][j] = (f32x4){0.f, 0.f, 0.f, 0.f};

    // ---- staging helpers (coalesced) ----
    auto stageB = [&](int half, int k0) {
#pragma unroll
        for (int p = 0; p < 4; ++p) {
            int q   = p * 4 + wid;                 // 16-row group 0..15
            int row = q * 16 + rsel;               // Bt row = C col
            gload16(Bt + (size_t)row * K + k0 + csel * 8, &Bs[half][q * 512]);
        }
    };
    auto stageA0 = [&](int half, int k0) {         // bf16 A via gload_lds
        const unsigned short* Ap; int lda, kb;
        if (k0 < KS) { Ap = (const unsigned short*)A1v; lda = lda1; kb = k0; }
        else         { Ap = (const unsigned short*)A2v; lda = lda2; kb = k0 - KS; }
        int gm = bm + wid * 16 + rsel; if (gm >= M) gm = M - 1;
        gload16(Ap + (size_t)gm * lda + kb + csel * 8, &As[half][wid * 512]);
    };
    auto loadA1 = [&](int k0, float4& u0, float4& u1) {   // f32 A -> regs
        const float* Ap = (const float*)A1v;
        int row = tid >> 2, seg = tid & 3;
        int gm = bm + row; if (gm >= M) gm = M - 1;
        const float* p = Ap + (size_t)gm * lda1 + k0 + seg * 8;
        u0 = *(const float4*)p;
        u1 = *(const float4*)(p + 4);
    };
    auto writeA1 = [&](int half, float4 u0, float4 u1) {  // cvt + ds_write
        u16x8 o;
        o[0] = f2b(u0.x); o[1] = f2b(u0.y); o[2] = f2b(u0.z); o[3] = f2b(u0.w);
        o[4] = f2b(u1.x); o[5] = f2b(u1.y); o[6] = f2b(u1.z); o[7] = f2b(u1.w);
        *(u16x8*)&As[half][tid * 8] = o;     // row-major image [64][32]
    };
    auto compute = [&](int half) {
        bf16x8 af[4], bfr[4];
#pragma unroll
        for (int i = 0; i < 4; ++i) {
            af[i]  = *(const bf16x8*)&As[half][((i * 16 + lrow) * 4 + lk) * 8];
            bfr[i] = *(const bf16x8*)&Bs[half][((wn + i * 16 + lrow) * 4 + lk) * 8];
        }
#pragma unroll
        for (int i = 0; i < 4; ++i)
#pragma unroll
            for (int j = 0; j < 4; ++j)
                acc[i][j] = __builtin_amdgcn_mfma_f32_16x16x32_bf16(
                    af[i], bfr[j], acc[i][j], 0, 0, 0);
    };

    // ---- prologue: stage tile 0 ----
    if (ADT == 0) {
        stageA0(0, 0);
    } else {
        float4 a0, a1;
        loadA1(0, a0, a1);
        writeA1(0, a0, a1);
    }
    stageB(0, 0);

    // ---- main loop: sync (drain tile t) -> issue t+1 -> compute t ----
    int cur = 0;
    for (int t = 0; t < NT; ++t) {
        __syncthreads();
        const bool pf = (t + 1 < NT);
        float4 pa0, pa1;
        if (pf) {
            if (ADT == 0) stageA0(cur ^ 1, (t + 1) * 32);
            else          loadA1((t + 1) * 32, pa0, pa1);
            stageB(cur ^ 1, (t + 1) * 32);
        }
        compute(cur);                        // overlaps t+1's memory time
        if (pf && ADT == 1) writeA1(cur ^ 1, pa0, pa1);
        cur ^= 1;
    }

    // ---- epilogue ----
    if (EPI == 2) {
#pragma unroll
        for (int i = 0; i < 4; ++i) {
#pragma unroll
            for (int j = 0; j < 4; ++j) {
                int col = wn + j * 16 + lrow;
                float bb = bias[col];
                f32x4 v = acc[i][j];
#pragma unroll
                for (int e = 0; e < 4; ++e) {
                    int gm = bm + i * 16 + lk * 4 + e;
                    if (gm < M)
                        C[(size_t)gm * HH + col] = f2b(fmaxf(v[e] + bb, 0.f));
                }
            }
        }
    } else {   // EPI == 3 : fused LayerNorm
        float sum_[4][4] = {};
        float sq_[4][4]  = {};
#pragma unroll
        for (int i = 0; i < 4; ++i)
#pragma unroll
            for (int j = 0; j < 4; ++j) {
                int col = wn + j * 16 + lrow;
                float tb = bias[col];
#pragma unroll
                for (int e = 0; e < 4; ++e) {
                    int gm = bm + i * 16 + lk * 4 + e;
                    if (gm >= M) gm = M - 1;
                    float o = acc[i][j][e] + add[(size_t)gm * HH + col] + tb;
                    acc[i][j][e] = o;
                    sum_[i][e] += o;
                    sq_[i][e]  += o * o;
                }
            }
#pragma unroll
        for (int m = 1; m < 16; m <<= 1)
#pragma unroll
            for (int i = 0; i < 4; ++i)
#pragma unroll
                for (int e = 0; e < 4; ++e) {
                    sum_[i][e] += __shfl_xor(sum_[i][e], m);
                    sq_[i][e]  += __shfl_xor(sq_[i][e],  m);
                }
        if (lrow == 0) {
#pragma unroll
            for (int i = 0; i < 4; ++i)
#pragma unroll
                for (int e = 0; e < 4; ++e) {
                    int rl = i * 16 + lk * 4 + e;
                    lredS[rl][wid] = sum_[i][e];
                    lredQ[rl][wid] = sq_[i][e];
                }
        }
        __syncthreads();
        float mus[4][4], rstds[4][4];
#pragma unroll
        for (int i = 0; i < 4; ++i)
#pragma unroll
            for (int e = 0; e < 4; ++e) {
                int rl = i * 16 + lk * 4 + e;
                float4 s4 = *(const float4*)lredS[rl];
                float4 q4 = *(const float4*)lredQ[rl];
                float mu = (s4.x + s4.y + s4.z + s4.w) * (1.0f / HH);
                float mq = (q4.x + q4.y + q4.z + q4.w) * (1.0f / HH);
                float var = mq - mu * mu;
                mus[i][e]   = mu;
                rstds[i][e] = rsqrtf(var + 1e-5f);
            }
#pragma unroll
        for (int i = 0; i < 4; ++i)
#pragma unroll
            for (int j = 0; j < 4; ++j) {
                int col = wn + j * 16 + lrow;
                float gg = lng[col], bb = lnb[col];
#pragma unroll
                for (int e = 0; e < 4; ++e) {
                    int gm = bm + i * 16 + lk * 4 + e;
                    if (gm < M) {
                        float o = gg * (acc[i][j][e] - mus[i][e]) * rstds[i][e] + bb;
                        C[(size_t)gm * HH + col] = f2b(o);
                    }
                }
            }
    }
}

// ---------------------------------------------------------------------------
// cast f32 -> bf16 (for W)
// ---------------------------------------------------------------------------
__global__ void cast4_k(const float* __restrict__ in, unsigned short* __restrict__ out,
                        int n4)
{
    int i = blockIdx.x * blockDim.x + threadIdx.x;
    if (i >= n4) return;
    float4 v = *(const float4*)(in + (size_t)i * 4);
    ushort4 o;
    o.x = f2b(v.x); o.y = f2b(v.y); o.z = f2b(v.z); o.w = f2b(v.w);
    *(ushort4*)(out + (size_t)i * 4) = o;
}

// transpose-cast basis/root into Bt[256][2304] per layer
__global__ __launch_bounds__(256) void tcast_k(
    const float* __restrict__ basis1, const float* __restrict__ root1,
    const float* __restrict__ basis2, const float* __restrict__ root2,
    unsigned short* __restrict__ Bt1, unsigned short* __restrict__ Bt2)
{
    __shared__ float Ls[64][68];
    int z = blockIdx.z;
    int layer = z / 9, m = z % 9;
    const float* src = layer ? (m < 8 ? basis2 + m * 65536 : root2)
                             : (m < 8 ? basis1 + m * 65536 : root1);
    unsigned short* dst = layer ? Bt2 : Bt1;
    int coloff = (m < 8) ? m * 256 : 2048;
    int ft = blockIdx.x * 64, dt = blockIdx.y * 64;
    int tid = threadIdx.x;
    int rr = tid >> 4, c4 = (tid & 15) << 2;
#pragma unroll
    for (int p = 0; p < 4; ++p) {
        int dl = p * 16 + rr;
        float4 v = *(const float4*)(src + (size_t)(dt + dl) * HH + ft + c4);
        Ls[c4 + 0][dl] = v.x; Ls[c4 + 1][dl] = v.y;
        Ls[c4 + 2][dl] = v.z; Ls[c4 + 3][dl] = v.w;
    }
    __syncthreads();
#pragma unroll
    for (int q = 0; q < 4; ++q) {
        int fl = q * 16 + rr;
        ushort4 o;
        o.x = f2b(Ls[fl][c4 + 0]); o.y = f2b(Ls[fl][c4 + 1]);
        o.z = f2b(Ls[fl][c4 + 2]); o.w = f2b(Ls[fl][c4 + 3]);
        *(ushort4*)(dst + (size_t)(ft + fl) * 2304 + coloff + dt + c4) = o;
    }
}

// ---------------------------------------------------------------------------
// CSR build
// ---------------------------------------------------------------------------
__global__ void hist_k(const int* __restrict__ dst, int* __restrict__ cnt)
{
    int i = blockIdx.x * blockDim.x + threadIdx.x;
    if (i < EE) atomicAdd(&cnt[dst[i]], 1);
}

__global__ void scan_blk_k(const int* __restrict__ cnt, int* __restrict__ rp,
                           int* __restrict__ bsum)
{
    __shared__ int s[256];
    int tid = threadIdx.x;
    int d = blockIdx.x * 256 + tid;
    int v = (d < NN) ? cnt[d] : 0;
    s[tid] = v;
    __syncthreads();
#pragma unroll
    for (int o = 1; o < 256; o <<= 1) {
        int t = (tid >= o) ? s[tid - o] : 0;
        __syncthreads();
        s[tid] += t;
        __syncthreads();
    }
    if (d < NN) rp[d] = s[tid] - v;
    if (tid == 255) bsum[blockIdx.x] = s[255];
}

__global__ void scan_top_k(int* __restrict__ bsum, int* __restrict__ boff, int nb)
{
    __shared__ int s[256];
    int tid = threadIdx.x;
    int v = (tid < nb) ? bsum[tid] : 0;
    s[tid] = v;
    __syncthreads();
#pragma unroll
    for (int o = 1; o < 256; o <<= 1) {
        int t = (tid >= o) ? s[tid - o] : 0;
        __syncthreads();
        s[tid] += t;
        __syncthreads();
    }
    if (tid < nb) boff[tid] = s[tid] - v;
}

__global__ void scan_add_k(int* __restrict__ rp, const int* __restrict__ boff,
                           int* __restrict__ cur, const int* __restrict__ cnt,
                           float* __restrict__ invdeg)
{
    int d = blockIdx.x * blockDim.x + threadIdx.x;
    if (d < NN) {
        int r = rp[d] + boff[d >> 8];
        rp[d] = r;
        cur[d] = r;
        invdeg[d] = 1.0f / fmaxf((float)cnt[d], 1.0f);
    }
    if (d == 0) rp[NN] = EE;
}

__global__ void scatter_k(const int* __restrict__ src, const int* __restrict__ dst,
                          const int* __restrict__ et, int* __restrict__ cur,
                          int* __restrict__ csr_src, int* __restrict__ csr_et)
{
    int e = blockIdx.x * blockDim.x + threadIdx.x;
    if (e >= EE) return;
    int p = atomicAdd(&cur[dst[e]], 1);
    csr_src[p] = src[e];
    csr_et[p]  = et[e];
}

// ---------------------------------------------------------------------------
// Aggregation (bf16 x -> bf16 y), one wave per dst node
// ---------------------------------------------------------------------------
__global__ __launch_bounds__(256) void agg_k(
    const unsigned short* __restrict__ x, const float* __restrict__ comp,
    const int* __restrict__ rp, const int* __restrict__ csr_src,
    const int* __restrict__ csr_et, const float* __restrict__ invdeg,
    unsigned short* __restrict__ y)
{
    int d = blockIdx.x * 4 + (threadIdx.x >> 6);
    if (d >= NN) return;
    int lane = threadIdx.x & 63;
    int beg = rp[d], end = rp[d + 1];

    float4 acc[NBB];
#pragma unroll
    for (int b = 0; b < NBB; ++b) acc[b] = make_float4(0.f, 0.f, 0.f, 0.f);

    for (int e = beg; e < end; ++e) {
        int s = csr_src[e];
        int t = csr_et[e];
        float4 c0 = *(const float4*)(comp + (size_t)t * NBB);
        float4 c1 = *(const float4*)(comp + (size_t)t * NBB + 4);
        ushort4 u = *(const ushort4*)(x + (size_t)s * HH + lane * 4);
        float xv0 = b2f(u.x), xv1 = b2f(u.y), xv2 = b2f(u.z), xv3 = b2f(u.w);
        float cc[NBB] = {c0.x, c0.y, c0.z, c0.w, c1.x, c1.y, c1.z, c1.w};
#pragma unroll
        for (int b = 0; b < NBB; ++b) {
            acc[b].x = fmaf(cc[b], xv0, acc[b].x);
            acc[b].y = fmaf(cc[b], xv1, acc[b].y);
            acc[b].z = fmaf(cc[b], xv2, acc[b].z);
            acc[b].w = fmaf(cc[b], xv3, acc[b].w);
        }
    }
    float sc = invdeg[d];
    unsigned short* yp = y + (size_t)d * (NBB * HH) + lane * 4;
#pragma unroll
    for (int b = 0; b < NBB; ++b) {
        ushort4 o;
        o.x = f2b(acc[b].x * sc); o.y = f2b(acc[b].y * sc);
        o.z = f2b(acc[b].z * sc); o.w = f2b(acc[b].w * sc);
        *(ushort4*)(yp + (size_t)b * HH) = o;
    }
}

// ---------------------------------------------------------------------------
// score (bf16 x, f32 rel)
// ---------------------------------------------------------------------------
__global__ __launch_bounds__(256) void score_k(
    const unsigned short* __restrict__ x, const float* __restrict__ rel,
    const int* __restrict__ heads, const int* __restrict__ rels,
    const int* __restrict__ tails, float* __restrict__ out)
{
    int i = blockIdx.x * 4 + (threadIdx.x >> 6);
    if (i >= TTT) return;
    int lane = threadIdx.x & 63;
    const unsigned short* h = x + (size_t)heads[i] * HH;
    const unsigned short* t = x + (size_t)tails[i] * HH;
    const float*          r = rel + (size_t)rels[i] * HH;
    int j = lane * 2;
    ushort2 hru = *(const ushort2*)(h + j), hiu = *(const ushort2*)(h + 128 + j);
    ushort2 tru = *(const ushort2*)(t + j), tiu = *(const ushort2*)(t + 128 + j);
    float2 rr = *(const float2*)(r + j), ri = *(const float2*)(r + 128 + j);
    float hr0 = b2f(hru.x), hr1 = b2f(hru.y), hi0 = b2f(hiu.x), hi1 = b2f(hiu.y);
    float tr0 = b2f(tru.x), tr1 = b2f(tru.y), ti0 = b2f(tiu.x), ti1 = b2f(tiu.y);
    float acc = hr0 * rr.x * tr0 + hi0 * rr.x * ti0
              + hr0 * ri.x * ti0 - hi0 * ri.x * tr0
              + hr1 * rr.y * tr1 + hi1 * rr.y * ti1
              + hr1 * ri.y * ti1 - hi1 * ri.y * tr1;
#pragma unroll
    for (int o = 1; o < 64; o <<= 1) acc += __shfl_xor(acc, o);
    if (lane == 0) out[i] = acc;
}

// ---------------------------------------------------------------------------
extern "C" void kernel_launch(void* const* d_in, const int* in_sizes, int n_in,
                              void* d_out, int out_size, void* d_ws, size_t ws_size,
                              hipStream_t stream)
{
    const float* ent_emb     = (const float*)d_in[0];
    const float* text_base   = (const float*)d_in[1];
    const float* text_proj_w = (const float*)d_in[2];
    const float* text_proj_b = (const float*)d_in[3];
    const float* ln_g        = (const float*)d_in[4];
    const float* ln_b        = (const float*)d_in[5];
    const float* comp1       = (const float*)d_in[6];
    const float* basis1      = (const float*)d_in[7];
    const float* root1       = (const float*)d_in[8];
    const float* bias1       = (const float*)d_in[9];
    const float* comp2       = (const float*)d_in[10];
    const float* basis2      = (const float*)d_in[11];
    const float* root2       = (const float*)d_in[12];
    const float* bias2       = (const float*)d_in[13];
    const float* rel_emb     = (const float*)d_in[14];
    const int*   edge_src    = (const int*)d_in[15];
    const int*   edge_dst    = (const int*)d_in[16];
    const int*   edge_type   = (const int*)d_in[17];
    const int*   heads       = (const int*)d_in[18];
    const int*   rels        = (const int*)d_in[19];
    const int*   tails       = (const int*)d_in[20];
    float* out = (float*)d_out;

    char* ws = (char*)d_ws;
    size_t off = 0;
    auto carve = [&](size_t bytes) -> void* {
        void* p = ws + off;
        off = (off + bytes + 255) & ~(size_t)255;
        return p;
    };
    unsigned short* x0b  = (unsigned short*)carve((size_t)NN * HH * 2);
    unsigned short* x1b  = (unsigned short*)carve((size_t)NN * HH * 2);
    unsigned short* y16  = (unsigned short*)carve((size_t)NN * NBB * HH * 2);
    unsigned short* W16  = (unsigned short*)carve((size_t)HH * TDD * 2);
    unsigned short* Bt1  = (unsigned short*)carve((size_t)HH * 2304 * 2);
    unsigned short* Bt2  = (unsigned short*)carve((size_t)HH * 2304 * 2);
    int*   cnt     = (int*)  carve((size_t)NN * 4);
    int*   rp      = (int*)  carve((size_t)(NN + 1) * 4);
    int*   cur     = (int*)  carve((size_t)NN * 4);
    float* invdeg  = (float*)carve((size_t)NN * 4);
    int*   csr_src = (int*)  carve((size_t)EE * 4);
    int*   csr_et  = (int*)  carve((size_t)EE * 4);
    int*   bsum    = (int*)  carve(256 * 4);
    int*   boff    = (int*)  carve(256 * 4);

    const dim3 blk(256);
    const int NBLK = (NN + 255) / 256;
    const int GG = (NN + 63) / 64;              // 782 blocks

    // ---- CSR build ----
    hipMemsetAsync(cnt, 0, (size_t)NN * 4, stream);
    hist_k<<<(EE + 255) / 256, blk, 0, stream>>>(edge_dst, cnt);
    scan_blk_k<<<NBLK, blk, 0, stream>>>(cnt, rp, bsum);
    scan_top_k<<<1, blk, 0, stream>>>(bsum, boff, NBLK);
    scan_add_k<<<NBLK, blk, 0, stream>>>(rp, boff, cur, cnt, invdeg);
    scatter_k<<<(EE + 255) / 256, blk, 0, stream>>>(
        edge_src, edge_dst, edge_type, cur, csr_src, csr_et);

    // ---- weight casts (small) ----
    cast4_k<<<(HH * TDD / 4 + 255) / 256, blk, 0, stream>>>(text_proj_w, W16, HH * TDD / 4);
    tcast_k<<<dim3(4, 4, 18), blk, 0, stream>>>(basis1, root1, basis2, root2, Bt1, Bt2);

    // ---- proj + fused LN:  x0b = LN(text_base @ W^T + ent_emb + b) ----
    gemm16_k<3, 1><<<GG, blk, 0, stream>>>(
        text_base, TDD, text_base, TDD, TDD, W16, TDD,
        x0b, NN, ent_emb, text_proj_b, ln_g, ln_b);

    // ---- two RGCN layers ----
    for (int layer = 0; layer < 2; ++layer) {
        const unsigned short* xin  = layer ? x1b : x0b;
        unsigned short*       xout = layer ? x0b : x1b;
        const unsigned short* Bt   = layer ? Bt2 : Bt1;
        const float*          comp = layer ? comp2 : comp1;
        const float*          bias = layer ? bias2 : bias1;

        agg_k<<<(NN + 3) / 4, blk, 0, stream>>>(
            xin, comp, rp, csr_src, csr_et, invdeg, y16);

        gemm16_k<2, 0><<<GG, blk, 0, stream>>>(
            y16, NBB * HH, xin, HH, NBB * HH, Bt, NBB * HH + HH,
            xout, NN, nullptr, bias, nullptr, nullptr);
    }

    // ---- scoring ----
    score_k<<<(TTT + 3) / 4, blk, 0, stream>>>(x0b, rel_emb, heads, rels, tails, out);
}